// Round 8
// baseline (232.438 us; speedup 1.0000x reference)
//
#include <hip/hip_runtime.h>
#include <math.h>

// Round 8:
//   prep   = cvt(fp32->bf16 activations+weights) + wc-softmax (wave-per-row),
//            one launch (3712 blocks).
//   gemm_qkv: R7 pipelined core; z==2 (V) epilogue writes Vt transposed
//            directly (vtrans kernel eliminated).
//   flash  : 128 q-rows/block (512 blocks = 2/CU exact), K/V LDS
//            double-buffer -> ONE barrier/iter, hoisted ak/av frags shared
//            by both q-subtiles, register prefetch of K/V/G.
//   gemm_wo: unchanged (BM=64, fp32 out).

#define BS 8
#define SEQ 1024
#define DM 512
#define NH 8
#define DK 64
#define ROWS (BS * SEQ)

typedef __bf16 bf16_t;
typedef bf16_t bf16x8 __attribute__((ext_vector_type(8)));
typedef bf16_t bf16x4 __attribute__((ext_vector_type(4)));
typedef float f32x4 __attribute__((ext_vector_type(4)));

__device__ inline f32x4 mfma32(bf16x8 a, bf16x8 b, f32x4 c) {
  return __builtin_amdgcn_mfma_f32_16x16x32_bf16(a, b, c, 0, 0, 0);
}

__device__ inline void gload_lds16(const bf16_t* g, bf16_t* l) {
  __builtin_amdgcn_global_load_lds(
      (const __attribute__((address_space(1))) void*)g,
      (__attribute__((address_space(3))) void*)l, 16, 0, 0);
}

// ---------------------------------------------------------------------------
// prep: blocks [0,1664) cvt fp32->bf16 (acts 1536 + weights 128);
//       blocks [1664,3712) wc-softmax, one wave per row, G = 1+softmax(wc).
// ---------------------------------------------------------------------------
__global__ __launch_bounds__(256) void prep_kernel(
    const float* q, const float* k, const float* v,
    const float* wq, const float* wk, const float* wv, const float* wo,
    const float* wc,
    bf16_t* xq, bf16_t* xk, bf16_t* xv,
    bf16_t* wqb, bf16_t* wkb, bf16_t* wvb, bf16_t* wob,
    bf16_t* G) {
  int blk = blockIdx.x;
  int t = threadIdx.x;
  if (blk < 1664) {
    const float* srcs[7] = {q, k, v, wq, wk, wv, wo};
    bf16_t* dsts[7] = {xq, xk, xv, wqb, wkb, wvb, wob};
    int seg, boff;
    if (blk < 1536) { seg = blk >> 9; boff = blk & 511; }
    else { seg = 3 + ((blk - 1536) >> 5); boff = (blk - 1536) & 31; }
    const float* src = srcs[seg] + (size_t)boff * 8192;
    bf16_t* dst = dsts[seg] + (size_t)boff * 8192;
#pragma unroll
    for (int f = 0; f < 8; ++f) {
      int idx = (f * 256 + t) * 4;
      float4 x = *(const float4*)(src + idx);
      bf16x4 o;
      o[0] = (bf16_t)x.x; o[1] = (bf16_t)x.y; o[2] = (bf16_t)x.z; o[3] = (bf16_t)x.w;
      *(bf16x4*)(dst + idx) = o;
    }
  } else {
    int row = (blk - 1664) * 4 + (t >> 6);  // 0..8191
    int l = t & 63;
    const float* x = wc + (size_t)row * SEQ;
    bf16_t* y = G + (size_t)row * SEQ;
    float4 vv[4];
#pragma unroll
    for (int j = 0; j < 4; ++j) vv[j] = *(const float4*)(x + l * 4 + j * 256);
    float m = -INFINITY;
#pragma unroll
    for (int j = 0; j < 4; ++j)
      m = fmaxf(m, fmaxf(fmaxf(vv[j].x, vv[j].y), fmaxf(vv[j].z, vv[j].w)));
#pragma unroll
    for (int off = 1; off < 64; off <<= 1) m = fmaxf(m, __shfl_xor(m, off, 64));
    float4 e[4];
    float s = 0.f;
#pragma unroll
    for (int j = 0; j < 4; ++j) {
      e[j].x = __expf(vv[j].x - m); e[j].y = __expf(vv[j].y - m);
      e[j].z = __expf(vv[j].z - m); e[j].w = __expf(vv[j].w - m);
      s += e[j].x + e[j].y + e[j].z + e[j].w;
    }
#pragma unroll
    for (int off = 1; off < 64; off <<= 1) s += __shfl_xor(s, off, 64);
    float inv = 1.0f / s;
#pragma unroll
    for (int j = 0; j < 4; ++j) {
      bf16x4 g;
      g[0] = (bf16_t)(1.0f + e[j].x * inv);
      g[1] = (bf16_t)(1.0f + e[j].y * inv);
      g[2] = (bf16_t)(1.0f + e[j].z * inv);
      g[3] = (bf16_t)(1.0f + e[j].w * inv);
      *(bf16x4*)(y + l * 4 + j * 256) = g;
    }
  }
}

// ---------------------------------------------------------------------------
// Core bf16 GEMM (R7 pipeline): C = X @ W^T + bias.  BN=128, BK=32.
// vt_out (runtime, block-uniform): write C transposed into Vt[bh][d][m].
// ---------------------------------------------------------------------------
template <int BM, bool OUTF32>
__device__ inline void gemm_core(const bf16_t* X, const bf16_t* W,
                                 const float* bias, void* Cv,
                                 int mblk, int nblk, bool vt_out) {
  __shared__ bf16_t As[2][BM * 32];
  __shared__ bf16_t Bs[2][128 * 32];
  int t = threadIdx.x, lane = t & 63, w = t >> 6;
  int quad = lane >> 4, l15 = lane & 15;
  constexpr int MT = BM / 32;
  int m0w = (w & 1) * (BM / 2), n0w = (w >> 1) * 64;
  int mbase = mblk * BM, nbase = nblk * 128;
  int lr = lane >> 2, l4 = lane & 3;
  f32x4 acc[MT][4] = {};

#pragma unroll
  for (int f = 0; f < BM / 64; ++f) {
    int i = f * 4 + w;
    gload_lds16(X + (size_t)(mbase + i * 16 + lr) * DM + l4 * 8, &As[0][i * 512]);
  }
#pragma unroll
  for (int f = 0; f < 2; ++f) {
    int i = f * 4 + w;
    gload_lds16(W + (size_t)(nbase + i * 16 + lr) * DM + l4 * 8, &Bs[0][i * 512]);
  }

  for (int it = 0; it < 16; ++it) {
    __syncthreads();
    int cb = it & 1;
    if (it + 1 < 16) {
      int kb = (it + 1) * 32, nb = (it + 1) & 1;
#pragma unroll
      for (int f = 0; f < BM / 64; ++f) {
        int i = f * 4 + w;
        gload_lds16(X + (size_t)(mbase + i * 16 + lr) * DM + kb + l4 * 8, &As[nb][i * 512]);
      }
#pragma unroll
      for (int f = 0; f < 2; ++f) {
        int i = f * 4 + w;
        gload_lds16(W + (size_t)(nbase + i * 16 + lr) * DM + kb + l4 * 8, &Bs[nb][i * 512]);
      }
    }
    bf16x8 af[MT], bfr[4];
#pragma unroll
    for (int mt = 0; mt < MT; ++mt)
      af[mt] = *(const bf16x8*)&As[cb][(m0w + mt * 16 + l15) * 32 + quad * 8];
#pragma unroll
    for (int nt = 0; nt < 4; ++nt)
      bfr[nt] = *(const bf16x8*)&Bs[cb][(n0w + nt * 16 + l15) * 32 + quad * 8];
#pragma unroll
    for (int mt = 0; mt < MT; ++mt)
#pragma unroll
      for (int nt = 0; nt < 4; ++nt)
        acc[mt][nt] = mfma32(af[mt], bfr[nt], acc[mt][nt]);
  }

  if (vt_out) {
    // Vt[((b*8 + col/64)*64 + col%64)*SEQ + m], 4 consecutive m per lane
#pragma unroll
    for (int nt = 0; nt < 4; ++nt) {
      int col = nbase + n0w + nt * 16 + l15;
      float bc = bias[col];
#pragma unroll
      for (int mt = 0; mt < MT; ++mt) {
        int row = mbase + m0w + mt * 16 + quad * 4;
        int bb = row >> 10, ml = row & 1023;
        bf16x4 vv;
#pragma unroll
        for (int r = 0; r < 4; ++r) vv[r] = (bf16_t)(acc[mt][nt][r] + bc);
        *(bf16x4*)&((bf16_t*)Cv)[((size_t)((bb * NH + (col >> 6)) * DK + (col & 63))) * SEQ + ml] = vv;
      }
    }
  } else {
#pragma unroll
    for (int nt = 0; nt < 4; ++nt) {
      int col = nbase + n0w + nt * 16 + l15;
      float bc = bias[col];
#pragma unroll
      for (int mt = 0; mt < MT; ++mt)
#pragma unroll
        for (int r = 0; r < 4; ++r) {
          int row = mbase + m0w + mt * 16 + quad * 4 + r;
          float vv = acc[mt][nt][r] + bc;
          if (OUTF32)
            ((float*)Cv)[(size_t)row * DM + col] = vv;
          else
            ((bf16_t*)Cv)[(size_t)row * DM + col] = (bf16_t)vv;
        }
    }
  }
}

__global__ __launch_bounds__(256) void gemm_qkv_kernel(
    const bf16_t* xq, const bf16_t* xk, const bf16_t* xv,
    const bf16_t* wq, const bf16_t* wk, const bf16_t* wv,
    const float* bq, const float* bk, const float* bv,
    bf16_t* cq, bf16_t* ck, bf16_t* vt) {
  const bf16_t* Xarr[3] = {xq, xk, xv};
  const bf16_t* Warr[3] = {wq, wk, wv};
  const float* barr[3] = {bq, bk, bv};
  bf16_t* Carr[3] = {cq, ck, vt};
  int z = blockIdx.z;
  gemm_core<128, false>(Xarr[z], Warr[z], barr[z], Carr[z],
                        blockIdx.x, blockIdx.y, z == 2);
}

__global__ __launch_bounds__(256) void gemm_wo_kernel(const bf16_t* X, const bf16_t* W,
                                                      const float* bias, float* C) {
  gemm_core<64, true>(X, W, bias, C, blockIdx.x, blockIdx.y, false);
}

// ---------------------------------------------------------------------------
// Flash attention: 128 q-rows x (h,b) per block; 4 waves, 32 q each (2 subs).
// K/V double-buffered in LDS -> single barrier per kv-tile.  S^T=mfma(K,Q),
// softmax per q=l15, wave-private LDS P, O^T += V^T P^T.
// ---------------------------------------------------------------------------
__global__ __launch_bounds__(256) void flash_mfma_kernel(const bf16_t* __restrict__ Qb,
                                                         const bf16_t* __restrict__ Kb,
                                                         const bf16_t* __restrict__ Vt,
                                                         const bf16_t* __restrict__ G,
                                                         bf16_t* __restrict__ Ab) {
  int qt = blockIdx.x, h = blockIdx.y, b = blockIdx.z;
  __shared__ bf16_t Qs[128][72];
  __shared__ bf16_t Ks[2][64][72];
  __shared__ bf16_t Vs[2][64][72];  // [buf][d][kv]
  __shared__ bf16_t Ps[128][72];    // [q][kv], rows wave-private
  int t = threadIdx.x, lane = t & 63, w = t >> 6;
  int quad = lane >> 4, l15 = lane & 15;

  // stage Q (128 rows)
#pragma unroll
  for (int f = 0; f < 4; ++f) {
    int chunk = t + f * 256;
    int row = chunk >> 3, k8 = (chunk & 7) * 8;
    *(bf16x8*)&Qs[row][k8] =
        *(const bf16x8*)&Qb[(size_t)(b * SEQ + qt * 128 + row) * DM + h * DK + k8];
  }

  // K/V staging map (64 rows x 64)
  int srow[2], sk8[2];
#pragma unroll
  for (int f = 0; f < 2; ++f) {
    int chunk = t + f * 256;
    srow[f] = chunk >> 3;
    sk8[f] = (chunk & 7) * 8;
  }
  const bf16_t* Kbase = Kb + (size_t)b * SEQ * DM + h * DK;
  const bf16_t* Vbase = Vt + (size_t)(b * NH + h) * DK * SEQ;
  bf16x8 kreg[2], vreg[2];
#pragma unroll
  for (int f = 0; f < 2; ++f) {
    kreg[f] = *(const bf16x8*)&Kbase[(size_t)srow[f] * DM + sk8[f]];
    vreg[f] = *(const bf16x8*)&Vbase[(size_t)srow[f] * SEQ + sk8[f]];
  }
#pragma unroll
  for (int f = 0; f < 2; ++f) {
    *(bf16x8*)&Ks[0][srow[f]][sk8[f]] = kreg[f];  // tile 0 -> buf 0
    *(bf16x8*)&Vs[0][srow[f]][sk8[f]] = vreg[f];
  }
#pragma unroll
  for (int f = 0; f < 2; ++f) {  // prefetch tile 1
    kreg[f] = *(const bf16x8*)&Kbase[(size_t)(64 + srow[f]) * DM + sk8[f]];
    vreg[f] = *(const bf16x8*)&Vbase[(size_t)srow[f] * SEQ + 64 + sk8[f]];
  }

  size_t grow[2];
  bf16x4 greg[2][4];
#pragma unroll
  for (int sub = 0; sub < 2; ++sub) {
    grow[sub] = (size_t)(b * SEQ + qt * 128 + w * 32 + sub * 16 + l15) * SEQ;
#pragma unroll
    for (int ct = 0; ct < 4; ++ct)
      greg[sub][ct] = *(const bf16x4*)&G[grow[sub] + ct * 16 + quad * 4];
  }

  __syncthreads();  // publish Qs + tile 0
  bf16x8 aq[2][2];
#pragma unroll
  for (int sub = 0; sub < 2; ++sub) {
    int qr = w * 32 + sub * 16 + l15;
    aq[sub][0] = *(const bf16x8*)&Qs[qr][quad * 8];
    aq[sub][1] = *(const bf16x8*)&Qs[qr][32 + quad * 8];
  }

  float m_st[2] = {-INFINITY, -INFINITY}, l_st[2] = {0.f, 0.f};
  f32x4 o[2][4] = {};

  for (int mt = 0; mt < 16; ++mt) {
    __syncthreads();  // publish tile mt writes; protect buf being overwritten
    int cb = mt & 1;
    if (mt + 1 < 16) {
      int nb = (mt + 1) & 1;
#pragma unroll
      for (int f = 0; f < 2; ++f) {
        *(bf16x8*)&Ks[nb][srow[f]][sk8[f]] = kreg[f];  // loads are 1 iter old
        *(bf16x8*)&Vs[nb][srow[f]][sk8[f]] = vreg[f];
      }
      if (mt + 2 < 16) {
#pragma unroll
        for (int f = 0; f < 2; ++f) {
          kreg[f] = *(const bf16x8*)&Kbase[(size_t)((mt + 2) * 64 + srow[f]) * DM + sk8[f]];
          vreg[f] = *(const bf16x8*)&Vbase[(size_t)srow[f] * SEQ + (mt + 2) * 64 + sk8[f]];
        }
      }
    }

    // hoisted fragments (shared by both q-subtiles)
    bf16x8 ak[4][2], av[4][2];
#pragma unroll
    for (int ct = 0; ct < 4; ++ct) {
      ak[ct][0] = *(const bf16x8*)&Ks[cb][ct * 16 + l15][quad * 8];
      ak[ct][1] = *(const bf16x8*)&Ks[cb][ct * 16 + l15][32 + quad * 8];
    }
#pragma unroll
    for (int dt = 0; dt < 4; ++dt) {
      av[dt][0] = *(const bf16x8*)&Vs[cb][dt * 16 + l15][quad * 8];
      av[dt][1] = *(const bf16x8*)&Vs[cb][dt * 16 + l15][32 + quad * 8];
    }

#pragma unroll
    for (int sub = 0; sub < 2; ++sub) {
      f32x4 s[4];
#pragma unroll
      for (int ct = 0; ct < 4; ++ct) {
        f32x4 z = {};
        s[ct] = mfma32(ak[ct][1], aq[sub][1], mfma32(ak[ct][0], aq[sub][0], z));
      }
      float sv[4][4];
      float rm = -INFINITY;
#pragma unroll
      for (int ct = 0; ct < 4; ++ct) {
#pragma unroll
        for (int r = 0; r < 4; ++r) {
          float x = s[ct][r] * 0.125f * (float)greg[sub][ct][r];
          sv[ct][r] = x;
          rm = fmaxf(rm, x);
        }
      }
      if (mt + 1 < 16) {  // greg dead -> prefetch next under compute
#pragma unroll
        for (int ct = 0; ct < 4; ++ct)
          greg[sub][ct] = *(const bf16x4*)&G[grow[sub] + (mt + 1) * 64 + ct * 16 + quad * 4];
      }
      rm = fmaxf(rm, __shfl_xor(rm, 16, 64));
      rm = fmaxf(rm, __shfl_xor(rm, 32, 64));
      float mnew = fmaxf(m_st[sub], rm);
      float alpha = __expf(m_st[sub] - mnew);
      m_st[sub] = mnew;

      float rs = 0.f;
#pragma unroll
      for (int ct = 0; ct < 4; ++ct) {
        bf16x4 pb;
#pragma unroll
        for (int r = 0; r < 4; ++r) {
          float p = __expf(sv[ct][r] - mnew);
          pb[r] = (bf16_t)p;
          rs += p;
        }
        *(bf16x4*)&Ps[w * 32 + sub * 16 + l15][ct * 16 + quad * 4] = pb;
      }
      rs += __shfl_xor(rs, 16, 64);
      rs += __shfl_xor(rs, 32, 64);
      l_st[sub] = l_st[sub] * alpha + rs;

#pragma unroll
      for (int dt = 0; dt < 4; ++dt) {
        o[sub][dt][0] *= alpha; o[sub][dt][1] *= alpha;
        o[sub][dt][2] *= alpha; o[sub][dt][3] *= alpha;
      }
#pragma unroll
      for (int c = 0; c < 2; ++c) {
        bf16x8 bp = *(const bf16x8*)&Ps[w * 32 + sub * 16 + l15][c * 32 + quad * 8];
#pragma unroll
        for (int dt = 0; dt < 4; ++dt)
          o[sub][dt] = mfma32(av[dt][c], bp, o[sub][dt]);
      }
    }
  }

#pragma unroll
  for (int sub = 0; sub < 2; ++sub) {
    float linv = 1.0f / l_st[sub];
    size_t qrow = (size_t)(b * SEQ + qt * 128 + w * 32 + sub * 16 + l15);
#pragma unroll
    for (int dt = 0; dt < 4; ++dt)
#pragma unroll
      for (int r = 0; r < 4; ++r)
        Ab[qrow * DM + h * DK + dt * 16 + quad * 4 + r] = (bf16_t)(o[sub][dt][r] * linv);
  }
}

// ---------------------------------------------------------------------------
extern "C" void kernel_launch(void* const* d_in, const int* in_sizes, int n_in,
                              void* d_out, int out_size, void* d_ws, size_t ws_size,
                              hipStream_t stream) {
  const float* query = (const float*)d_in[0];
  const float* key = (const float*)d_in[1];
  const float* value = (const float*)d_in[2];
  const float* wc = (const float*)d_in[3];
  const float* Wq = (const float*)d_in[4];
  const float* bq = (const float*)d_in[5];
  const float* Wk = (const float*)d_in[6];
  const float* bk = (const float*)d_in[7];
  const float* Wv = (const float*)d_in[8];
  const float* bv = (const float*)d_in[9];
  const float* Wo = (const float*)d_in[10];
  const float* bo = (const float*)d_in[11];
  float* out = (float*)d_out;

  const size_t ACT = (size_t)ROWS * DM;
  const size_t WSZ = (size_t)DM * DM;
  bf16_t* Qb = (bf16_t*)d_ws;
  bf16_t* Kb = Qb + ACT;
  bf16_t* Vt = Kb + ACT;
  bf16_t* Ab = Vt + ACT;
  bf16_t* G = Ab + ACT;
  bf16_t* Xq = G + (size_t)BS * SEQ * SEQ;
  bf16_t* Xk = Xq + ACT;
  bf16_t* Xv = Xk + ACT;
  bf16_t* Wqb = Xv + ACT;
  bf16_t* Wkb = Wqb + WSZ;
  bf16_t* Wvb = Wkb + WSZ;
  bf16_t* Wob = Wvb + WSZ;

  prep_kernel<<<3712, 256, 0, stream>>>(query, key, value, Wq, Wk, Wv, Wo, wc,
                                        Xq, Xk, Xv, Wqb, Wkb, Wvb, Wob, G);

  gemm_qkv_kernel<<<dim3(ROWS / 128, DM / 128, 3), 256, 0, stream>>>(
      Xq, Xk, Xv, Wqb, Wkb, Wvb, bq, bk, bv, Qb, Kb, Vt);

  flash_mfma_kernel<<<dim3(SEQ / 128, NH, BS), 256, 0, stream>>>(Qb, Kb, Vt, G, Ab);

  gemm_wo_kernel<<<dim3(ROWS / 64, DM / 128), 256, 0, stream>>>(Ab, Wob, bo, out);
}